// Round 1
// baseline (688.452 us; speedup 1.0000x reference)
//
#include <hip/hip_runtime.h>
#include <math.h>

#define NN 512
#define BB 16
#define TOTAL (BB * NN * NN)   // 4,194,304 cells
#define EPS_F 1e-5f
#define DELTA_F 0.05f

// ---------------------------------------------------------------------------
// Init: read x_mix (float4 per cell: x0, x1, geom, bc), build Dirichlet mask
// and u0 = dir ? bc : 0.
// ---------------------------------------------------------------------------
__global__ __launch_bounds__(256) void init_kernel(
    const float* __restrict__ x_mix,
    float* __restrict__ u,
    unsigned char* __restrict__ mask)
{
    int idx = blockIdx.x * blockDim.x + threadIdx.x;
    if (idx >= TOTAL) return;
    int j = idx & (NN - 1);
    int i = (idx >> 9) & (NN - 1);
    float4 xm = reinterpret_cast<const float4*>(x_mix)[idx];
    float geom = xm.z;
    float bc   = xm.w;
    bool edge = (i == 0) | (i == NN - 1) | (j == 0) | (j == NN - 1);
    bool dir  = edge || (geom > 0.5f);
    mask[idx] = dir ? 1 : 0;
    u[idx]    = dir ? bc : 0.0f;
}

// ---------------------------------------------------------------------------
// One Jacobi step. Fluid cells are guaranteed interior (edges are Dirichlet),
// so idx +/- 1 and idx +/- NN never leave the (b,:,:) slab.
// Sum order matches jnp: u[i+1,j] + u[i-1,j] + u[i,j+1] + u[i,j-1].
// ---------------------------------------------------------------------------
__global__ __launch_bounds__(256) void jacobi_kernel(
    const float* __restrict__ uin,
    float* __restrict__ uout,
    const unsigned char* __restrict__ mask)
{
    int idx = blockIdx.x * blockDim.x + threadIdx.x;
    if (idx >= TOTAL) return;
    if (mask[idx]) {
        uout[idx] = uin[idx];
    } else {
        float s = ((uin[idx + NN] + uin[idx - NN]) + uin[idx + 1]) + uin[idx - 1];
        uout[idx] = 0.25f * s;
    }
}

// ---------------------------------------------------------------------------
// Epilogue: out = (u - y_mean)/(y_std + eps)
//               + w_outer(i,j) * [geom<=0.5] * 0.25*sigmoid(logit) * (x·w + b)
// ---------------------------------------------------------------------------
__global__ __launch_bounds__(256) void final_kernel(
    const float* __restrict__ x_mix,
    const float* __restrict__ u,
    const float* __restrict__ w_back,
    const float* __restrict__ b_back,
    const float* __restrict__ logit,
    const float* __restrict__ y_mean,
    const float* __restrict__ y_std,
    float* __restrict__ out)
{
    int idx = blockIdx.x * blockDim.x + threadIdx.x;
    if (idx >= TOTAL) return;
    int j = idx & (NN - 1);
    int i = (idx >> 9) & (NN - 1);

    float4 xm = reinterpret_cast<const float4*>(x_mix)[idx];

    float e = (u[idx] - y_mean[0]) / (y_std[0] + EPS_F);

    float r = xm.x * w_back[0] + xm.y * w_back[1] + b_back[0];

    float rs = 0.25f / (1.0f + expf(-logit[0]));

    float xs = (float)i * (1.0f / (float)(NN - 1));
    float ys = (float)j * (1.0f / (float)(NN - 1));
    float d  = fminf(fminf(xs, 1.0f - xs), fminf(ys, 1.0f - ys));
    float w  = fminf(fmaxf(d / DELTA_F, 0.0f), 1.0f);
    if (xm.z > 0.5f) w = 0.0f;

    out[idx] = e + w * rs * r;
}

// ---------------------------------------------------------------------------
extern "C" void kernel_launch(void* const* d_in, const int* in_sizes, int n_in,
                              void* d_out, int out_size, void* d_ws, size_t ws_size,
                              hipStream_t stream)
{
    const float* x_mix  = (const float*)d_in[0];
    const float* w_back = (const float*)d_in[1];
    const float* b_back = (const float*)d_in[2];
    const float* logit  = (const float*)d_in[3];
    const float* y_mean = (const float*)d_in[4];
    const float* y_std  = (const float*)d_in[5];

    float* out = (float*)d_out;

    // Workspace layout: u_a (16 MB floats) | mask (4 MB bytes)
    float* u_a = (float*)d_ws;
    unsigned char* mask = (unsigned char*)((char*)d_ws + (size_t)TOTAL * sizeof(float));
    float* u_b = out;  // use d_out as the second ping-pong buffer

    const int block = 256;
    const int grid  = (TOTAL + block - 1) / block;

    init_kernel<<<grid, block, 0, stream>>>(x_mix, u_a, mask);

    // 50 iterations, ping-pong. Even count -> final u lands in u_a (= d_ws).
    for (int it = 0; it < 50; ++it) {
        const float* src = (it & 1) ? u_b : u_a;
        float*       dst = (it & 1) ? u_a : u_b;
        jacobi_kernel<<<grid, block, 0, stream>>>(src, dst, mask);
    }

    final_kernel<<<grid, block, 0, stream>>>(x_mix, u_a, w_back, b_back,
                                             logit, y_mean, y_std, out);
}

// Round 2
// 314.659 us; speedup vs baseline: 2.1879x; 2.1879x over previous
//
#include <hip/hip_runtime.h>
#include <math.h>

#define NN 512
#define BB 16
#define TOTAL (BB * NN * NN)   // 4,194,304 cells
#define EPS_F 1e-5f
#define DELTA_F 0.05f

#define TILE 64
#define HALO 10
#define TT   10                 // Jacobi iterations fused per launch
#define LR   (TILE + 2*HALO)    // 84 LDS rows
#define LC   (TILE + 2*HALO)    // 84 LDS cols (stride; %4==0 for float4 alignment)
#define CG   (LC/4)             // 21 column groups of 4
#define GROUPS ((LR - 2) * CG)  // 82*21 = 1722 groups per iteration
#define GPT  7                  // ceil(1722/256) groups per thread

// ---------------------------------------------------------------------------
// Init: read x_mix (float4 per cell: x0, x1, geom, bc), build fluid coeff
// c (1=fluid, 0=Dirichlet) and u0 = dir ? bc : 0.
// ---------------------------------------------------------------------------
__global__ __launch_bounds__(256) void init_kernel(
    const float* __restrict__ x_mix,
    float* __restrict__ u,
    unsigned char* __restrict__ cmask)
{
    int idx = blockIdx.x * blockDim.x + threadIdx.x;
    if (idx >= TOTAL) return;
    int j = idx & (NN - 1);
    int i = (idx >> 9) & (NN - 1);
    float4 xm = reinterpret_cast<const float4*>(x_mix)[idx];
    bool edge = (i == 0) | (i == NN - 1) | (j == 0) | (j == NN - 1);
    bool dir  = edge || (xm.z > 0.5f);
    cmask[idx] = dir ? 0 : 1;
    u[idx]     = dir ? xm.w : 0.0f;
}

// ---------------------------------------------------------------------------
// Temporal-blocked stencil: TT Jacobi iterations on a 64x64 tile with
// HALO=TT halo, entirely in LDS. Ring cells frozen (c=0); validity-shrink
// guarantees the center 64x64 is exact after TT iterations.
// ---------------------------------------------------------------------------
__global__ __launch_bounds__(256) void stencil_kernel(
    const float* __restrict__ uin,
    float* __restrict__ uout,
    const unsigned char* __restrict__ cmask)
{
    __shared__ float us[2][LR][LC];
    __shared__ unsigned char cs[LR][LC];

    const int b  = blockIdx.z;
    const int oy = blockIdx.y * TILE;
    const int ox = blockIdx.x * TILE;
    const int tid = threadIdx.x;

    const float* ub = uin + (size_t)b * NN * NN;
    const unsigned char* cb = cmask + (size_t)b * NN * NN;

    // ---- load halo region (clamped) ----
    for (int k = tid; k < LR * LR; k += 256) {
        int r = k / LR;
        int c = k - r * LR;
        int gi = oy - HALO + r; gi = min(max(gi, 0), NN - 1);
        int gj = ox - HALO + c; gj = min(max(gj, 0), NN - 1);
        float v = ub[gi * NN + gj];
        unsigned char cv = cb[gi * NN + gj];
        if (r == 0 || r == LR - 1 || c == 0 || c == LR - 1) cv = 0; // freeze ring
        us[0][r][c] = v;
        us[1][r][c] = v;
        cs[r][c] = cv;
    }
    __syncthreads();

    // ---- precompute per-thread group element-offsets (keep div out of loop) ----
    int goff[GPT];
#pragma unroll
    for (int k = 0; k < GPT; ++k) {
        int g = tid + k * 256;
        if (g < GROUPS) {
            int r  = 1 + g / CG;
            int c4 = (g - (r - 1) * CG) * 4;
            goff[k] = r * LC + c4;
        } else {
            goff[k] = -1;
        }
    }

    // ---- TT fused Jacobi iterations ----
#pragma unroll 1
    for (int t = 0; t < TT; ++t) {
        const float* ur = &us[t & 1][0][0];
        float*       uw = &us[(t & 1) ^ 1][0][0];
#pragma unroll
        for (int k = 0; k < GPT; ++k) {
            int o = goff[k];
            if (o < 0) continue;
            float4 mid = *(const float4*)(ur + o);
            float4 top = *(const float4*)(ur + o - LC);
            float4 bot = *(const float4*)(ur + o + LC);
            float  lf  = ur[o - 1];
            float  rt  = ur[o + 4];
            uchar4 cc  = *(const uchar4*)(&cs[0][0] + o);
            float4 res;
            float s0 = (bot.x + top.x) + (mid.y + lf);
            float s1 = (bot.y + top.y) + (mid.z + mid.x);
            float s2 = (bot.z + top.z) + (mid.w + mid.y);
            float s3 = (bot.w + top.w) + (rt    + mid.z);
            res.x = cc.x ? 0.25f * s0 : mid.x;
            res.y = cc.y ? 0.25f * s1 : mid.y;
            res.z = cc.z ? 0.25f * s2 : mid.z;
            res.w = cc.w ? 0.25f * s3 : mid.w;
            *(float4*)(uw + o) = res;
        }
        __syncthreads();
    }

    // ---- store center 64x64 (TT even -> result in buffer 0) ----
    float* og = uout + (size_t)b * NN * NN;
    const float* uf = &us[TT & 1 ? 1 : 0][0][0];
    for (int k = tid; k < TILE * TILE; k += 256) {
        int r = k >> 6;
        int c = k & 63;
        og[(oy + r) * NN + (ox + c)] = uf[(HALO + r) * LC + (HALO + c)];
    }
}

// ---------------------------------------------------------------------------
// Epilogue: out = (u - y_mean)/(y_std + eps)
//               + w_outer(i,j) * [geom<=0.5] * 0.25*sigmoid(logit) * (x·w + b)
// In-place safe on u==out (each thread reads then writes its own cell).
// ---------------------------------------------------------------------------
__global__ __launch_bounds__(256) void final_kernel(
    const float* __restrict__ x_mix,
    const float* __restrict__ u,
    const float* __restrict__ w_back,
    const float* __restrict__ b_back,
    const float* __restrict__ logit,
    const float* __restrict__ y_mean,
    const float* __restrict__ y_std,
    float* __restrict__ out)
{
    int idx = blockIdx.x * blockDim.x + threadIdx.x;
    if (idx >= TOTAL) return;
    int j = idx & (NN - 1);
    int i = (idx >> 9) & (NN - 1);

    float4 xm = reinterpret_cast<const float4*>(x_mix)[idx];

    float e = (u[idx] - y_mean[0]) / (y_std[0] + EPS_F);

    float r = xm.x * w_back[0] + xm.y * w_back[1] + b_back[0];

    float rs = 0.25f / (1.0f + expf(-logit[0]));

    float xs = (float)i * (1.0f / (float)(NN - 1));
    float ys = (float)j * (1.0f / (float)(NN - 1));
    float d  = fminf(fminf(xs, 1.0f - xs), fminf(ys, 1.0f - ys));
    float w  = fminf(fmaxf(d / DELTA_F, 0.0f), 1.0f);
    if (xm.z > 0.5f) w = 0.0f;

    out[idx] = e + w * rs * r;
}

// ---------------------------------------------------------------------------
extern "C" void kernel_launch(void* const* d_in, const int* in_sizes, int n_in,
                              void* d_out, int out_size, void* d_ws, size_t ws_size,
                              hipStream_t stream)
{
    const float* x_mix  = (const float*)d_in[0];
    const float* w_back = (const float*)d_in[1];
    const float* b_back = (const float*)d_in[2];
    const float* logit  = (const float*)d_in[3];
    const float* y_mean = (const float*)d_in[4];
    const float* y_std  = (const float*)d_in[5];

    float* out = (float*)d_out;

    // Workspace layout: u_a (16 MB floats) | cmask (4 MB bytes)
    float* u_a = (float*)d_ws;
    unsigned char* cmask = (unsigned char*)((char*)d_ws + (size_t)TOTAL * sizeof(float));
    float* u_b = out;  // d_out doubles as the second ping-pong buffer

    const int block = 256;
    const int grid1d = (TOTAL + block - 1) / block;

    init_kernel<<<grid1d, block, 0, stream>>>(x_mix, u_a, cmask);

    // 50 iterations = 5 launches x TT(=10) fused steps.
    // a->b, b->a, a->b, b->a, a->b : final result in u_b == d_out.
    dim3 sgrid(NN / TILE, NN / TILE, BB);   // 8 x 8 x 16 = 1024 blocks
    for (int l = 0; l < 5; ++l) {
        const float* src = (l & 1) ? u_b : u_a;
        float*       dst = (l & 1) ? u_a : u_b;
        stencil_kernel<<<sgrid, block, 0, stream>>>(src, dst, cmask);
    }

    final_kernel<<<grid1d, block, 0, stream>>>(x_mix, u_b, w_back, b_back,
                                               logit, y_mean, y_std, out);
}

// Round 3
// 184.417 us; speedup vs baseline: 3.7331x; 1.7062x over previous
//
#include <hip/hip_runtime.h>
#include <math.h>

#define NN 512
#define BB 16
#define TOTAL (BB * NN * NN)   // 4,194,304 cells
#define EPS_F 1e-5f
#define DELTA_F 0.05f

#define HALO 16
#define LR   96                 // 64 + 2*HALO register tile
#define TTI  10                 // Jacobi iterations per launch (5 launches = 50)

// lane gets lane-1 (within each 16-lane DPP row); boundary lanes -> 0
__device__ __forceinline__ float dpp_shr1(float x) {
    int r = __builtin_amdgcn_update_dpp(0, __float_as_int(x), 0x111, 0xf, 0xf, true);
    return __int_as_float(r);
}
// lane gets lane+1; boundary lanes -> 0
__device__ __forceinline__ float dpp_shl1(float x) {
    int r = __builtin_amdgcn_update_dpp(0, __float_as_int(x), 0x101, 0xf, 0xf, true);
    return __int_as_float(r);
}

// ---------------------------------------------------------------------------
// Init: u0 = dir ? bc : 0 ; cmask = fluid(1)/dirichlet(0)
// ---------------------------------------------------------------------------
__global__ __launch_bounds__(256) void init_kernel(
    const float* __restrict__ x_mix,
    float* __restrict__ u,
    unsigned char* __restrict__ cmask)
{
    int idx = blockIdx.x * blockDim.x + threadIdx.x;
    if (idx >= TOTAL) return;
    int j = idx & (NN - 1);
    int i = (idx >> 9) & (NN - 1);
    float4 xm = reinterpret_cast<const float4*>(x_mix)[idx];
    bool edge = (i == 0) | (i == NN - 1) | (j == 0) | (j == NN - 1);
    bool dir  = edge || (xm.z > 0.5f);
    cmask[idx] = dir ? 0 : 1;
    u[idx]     = dir ? xm.w : 0.0f;
}

// ---------------------------------------------------------------------------
// Register-tile temporal-blocked stencil.
// 16x16 threads, each owns a 6x6 cell block of a 96x96 tile (64x64 output,
// halo 16 >= TTI). u lives in VGPRs; vertical halo via tiny transposed LDS
// exchange (conflict-free, double-buffered, 1 barrier/iter); horizontal halo
// via DPP lane shifts. Dirichlet coeffs packed as bytes in 9 VGPRs.
// ---------------------------------------------------------------------------
template<bool FINAL>
__global__ __launch_bounds__(256, 4) void stencil_kernel(
    const float* __restrict__ uin,
    float* __restrict__ uout,
    const unsigned char* __restrict__ cmask,
    const float* __restrict__ x_mix,
    const float* __restrict__ w_back,
    const float* __restrict__ b_back,
    const float* __restrict__ logit,
    const float* __restrict__ y_mean,
    const float* __restrict__ y_std)
{
    __shared__ float xup[2][6][256];   // each thread's row 0 (consumed by tr-1)
    __shared__ float xdn[2][6][256];   // each thread's row 5 (consumed by tr+1)

    const int b   = blockIdx.z;
    const int oy  = blockIdx.y * 64;
    const int ox  = blockIdx.x * 64;
    const int tid = threadIdx.x;
    const int tr  = tid >> 4;
    const int tc  = tid & 15;
    const int R0  = tr * 6;
    const int C0  = tc * 6;

    const float* ub = uin + (size_t)b * NN * NN;
    const unsigned char* cb = cmask + (size_t)b * NN * NN;

    float u[6][6];
    unsigned cfp[9];
#pragma unroll
    for (int w = 0; w < 9; ++w) cfp[w] = 0u;

    // ---- setup: load 6x6 u + coeff bytes (clamped; tile ring frozen) ----
#pragma unroll
    for (int r = 0; r < 6; ++r) {
        int ty = R0 + r;
        int gi = oy - HALO + ty;
        gi = min(max(gi, 0), NN - 1);
#pragma unroll
        for (int c = 0; c < 6; ++c) {
            int tx = C0 + c;
            int gj = ox - HALO + tx;
            gj = min(max(gj, 0), NN - 1);
            u[r][c] = ub[gi * NN + gj];
            unsigned m = cb[gi * NN + gj];
            bool ring = (ty == 0) | (ty == LR - 1) | (tx == 0) | (tx == LR - 1);
            if (ring) m = 0u;
            int idx = r * 6 + c;
            cfp[idx >> 2] |= m << (8 * (idx & 3));
        }
    }

    const int tup = (tid >= 16)  ? tid - 16 : tid;   // clamped neighbor indices
    const int tdn = (tid < 240)  ? tid + 16 : tid;

    // ---- TTI fused Jacobi iterations, all in registers ----
#pragma unroll 1
    for (int t = 0; t < TTI; ++t) {
        const int pb = t & 1;
        // publish OLD boundary rows (transposed layout: conflict-free b32)
#pragma unroll
        for (int w = 0; w < 6; ++w) {
            xup[pb][w][tid] = u[0][w];
            xdn[pb][w][tid] = u[5][w];
        }
        // capture OLD horizontal neighbor cols via DPP (pure VALU)
        float lsh[6], rsh[6];
#pragma unroll
        for (int r = 0; r < 6; ++r) {
            lsh[r] = dpp_shr1(u[r][5]);
            rsh[r] = dpp_shl1(u[r][0]);
        }
        __syncthreads();
        float th[6], bh[6];
#pragma unroll
        for (int w = 0; w < 6; ++w) {
            float a = xdn[pb][w][tup];
            th[w] = (tr > 0)  ? a : 0.0f;
            float d = xup[pb][w][tdn];
            bh[w] = (tr < 15) ? d : 0.0f;
        }
        // in-register raster update; orow/prow keep OLD values (pure SSA)
        float prow[6];
#pragma unroll
        for (int c = 0; c < 6; ++c) prow[c] = th[c];
#pragma unroll
        for (int r = 0; r < 6; ++r) {
            float orow[6];
#pragma unroll
            for (int c = 0; c < 6; ++c) orow[c] = u[r][c];
#pragma unroll
            for (int c = 0; c < 6; ++c) {
                float up = prow[c];
                float dn = (r < 5) ? u[r + 1][c] : bh[c];
                float lf = (c > 0) ? orow[c - 1] : lsh[r];
                float rt = (c < 5) ? orow[c + 1] : rsh[r];
                float s  = (up + dn) + (lf + rt);
                float od = orow[c];
                float tq = __builtin_fmaf(0.25f, s, -od);
                int idx  = r * 6 + c;
                float cf = (float)((cfp[idx >> 2] >> (8 * (idx & 3))) & 0xffu);
                u[r][c] = __builtin_fmaf(cf, tq, od);
            }
#pragma unroll
            for (int c = 0; c < 6; ++c) prow[c] = orow[c];
        }
    }

    // ---- store center 64x64 (optionally fused epilogue) ----
    float* og = uout + (size_t)b * NN * NN;
    if (!FINAL) {
#pragma unroll
        for (int r = 0; r < 6; ++r) {
            int ty = R0 + r - HALO;
#pragma unroll
            for (int c = 0; c < 6; ++c) {
                int tx = C0 + c - HALO;
                if ((unsigned)ty < 64u && (unsigned)tx < 64u)
                    og[(size_t)(oy + ty) * NN + (ox + tx)] = u[r][c];
            }
        }
    } else {
        float w0  = w_back[0], w1 = w_back[1], bb0 = b_back[0];
        float rs  = 0.25f / (1.0f + expf(-logit[0]));
        float ym  = y_mean[0];
        float ysd = y_std[0] + EPS_F;
        const float4* xm4 = (const float4*)x_mix;
#pragma unroll
        for (int r = 0; r < 6; ++r) {
            int ty = R0 + r - HALO;
#pragma unroll
            for (int c = 0; c < 6; ++c) {
                int tx = C0 + c - HALO;
                if ((unsigned)ty < 64u && (unsigned)tx < 64u) {
                    int gi = oy + ty, gj = ox + tx;
                    size_t gidx = (size_t)b * NN * NN + (size_t)gi * NN + gj;
                    float4 xm = xm4[gidx];
                    float e  = (u[r][c] - ym) / ysd;
                    float rr = xm.x * w0 + xm.y * w1 + bb0;
                    float xs = (float)gi * (1.0f / 511.0f);
                    float ys = (float)gj * (1.0f / 511.0f);
                    float dd = fminf(fminf(xs, 1.0f - xs), fminf(ys, 1.0f - ys));
                    float ww = fminf(fmaxf(dd * (1.0f / DELTA_F), 0.0f), 1.0f);
                    if (xm.z > 0.5f) ww = 0.0f;
                    og[(size_t)gi * NN + gj] = e + ww * rs * rr;
                }
            }
        }
    }
}

// ---------------------------------------------------------------------------
extern "C" void kernel_launch(void* const* d_in, const int* in_sizes, int n_in,
                              void* d_out, int out_size, void* d_ws, size_t ws_size,
                              hipStream_t stream)
{
    const float* x_mix  = (const float*)d_in[0];
    const float* w_back = (const float*)d_in[1];
    const float* b_back = (const float*)d_in[2];
    const float* logit  = (const float*)d_in[3];
    const float* y_mean = (const float*)d_in[4];
    const float* y_std  = (const float*)d_in[5];

    float* out = (float*)d_out;

    // Workspace: u_a (16 MB floats) | cmask (4 MB bytes)
    float* u_a = (float*)d_ws;
    unsigned char* cmask = (unsigned char*)((char*)d_ws + (size_t)TOTAL * sizeof(float));

    const int block = 256;
    const int grid1d = (TOTAL + block - 1) / block;

    init_kernel<<<grid1d, block, 0, stream>>>(x_mix, u_a, cmask);

    // 50 iters = 5 launches x TTI(=10). Chain: a->out->a->out->a->(FINAL)->out
    dim3 sgrid(NN / 64, NN / 64, BB);   // 8 x 8 x 16 = 1024 blocks (4/CU)
    stencil_kernel<false><<<sgrid, block, 0, stream>>>(u_a, out, cmask, x_mix,
        w_back, b_back, logit, y_mean, y_std);
    stencil_kernel<false><<<sgrid, block, 0, stream>>>(out, u_a, cmask, x_mix,
        w_back, b_back, logit, y_mean, y_std);
    stencil_kernel<false><<<sgrid, block, 0, stream>>>(u_a, out, cmask, x_mix,
        w_back, b_back, logit, y_mean, y_std);
    stencil_kernel<false><<<sgrid, block, 0, stream>>>(out, u_a, cmask, x_mix,
        w_back, b_back, logit, y_mean, y_std);
    stencil_kernel<true><<<sgrid, block, 0, stream>>>(u_a, out, cmask, x_mix,
        w_back, b_back, logit, y_mean, y_std);
}

// Round 4
// 156.675 us; speedup vs baseline: 4.3942x; 1.1771x over previous
//
#include <hip/hip_runtime.h>
#include <math.h>

#define NN 512
#define BB 16
#define TOTAL (BB * NN * NN)   // 4,194,304 cells
#define EPS_F 1e-5f
#define DELTA_F 0.05f

#define HALO 16
#define LR   96                 // 64 + 2*HALO register tile
#define TTI  10                 // Jacobi iterations per launch (5 launches = 50)

// lane gets lane-1 (within each 16-lane DPP row); boundary lanes -> 0
__device__ __forceinline__ float dpp_shr1(float x) {
    int r = __builtin_amdgcn_update_dpp(0, __float_as_int(x), 0x111, 0xf, 0xf, true);
    return __int_as_float(r);
}
// lane gets lane+1; boundary lanes -> 0
__device__ __forceinline__ float dpp_shl1(float x) {
    int r = __builtin_amdgcn_update_dpp(0, __float_as_int(x), 0x101, 0xf, 0xf, true);
    return __int_as_float(r);
}

// ---------------------------------------------------------------------------
// Init: u0 = dir ? bc : 0 ; cmask = fluid(1)/dirichlet(0)
// ---------------------------------------------------------------------------
__global__ __launch_bounds__(256) void init_kernel(
    const float* __restrict__ x_mix,
    float* __restrict__ u,
    unsigned char* __restrict__ cmask)
{
    int idx = blockIdx.x * blockDim.x + threadIdx.x;
    if (idx >= TOTAL) return;
    int j = idx & (NN - 1);
    int i = (idx >> 9) & (NN - 1);
    float4 xm = reinterpret_cast<const float4*>(x_mix)[idx];
    bool edge = (i == 0) | (i == NN - 1) | (j == 0) | (j == NN - 1);
    bool dir  = edge || (xm.z > 0.5f);
    cmask[idx] = dir ? 0 : 1;
    u[idx]     = dir ? xm.w : 0.0f;
}

// ---------------------------------------------------------------------------
// Register-tile temporal-blocked stencil.
// 16x16 threads, each owns a 6x6 block of a 96x96 tile (64x64 output,
// halo 16 >= TTI). u AND the fluid coefficients live in VGPRs; vertical halo
// via transposed conflict-free LDS (double-buffered, 1 barrier/iter);
// horizontal halo via DPP lane shifts. Ring cells frozen (cf=0) annihilate
// any garbage halo values through fma(cf, ., old), so no boundary selects.
// ---------------------------------------------------------------------------
template<bool FINAL>
__global__ __launch_bounds__(256, 2) void stencil_kernel(
    const float* __restrict__ uin,
    float* __restrict__ uout,
    const unsigned char* __restrict__ cmask,
    const float* __restrict__ x_mix,
    const float* __restrict__ w_back,
    const float* __restrict__ b_back,
    const float* __restrict__ logit,
    const float* __restrict__ y_mean,
    const float* __restrict__ y_std)
{
    __shared__ float xup[2][6][256];   // each thread's row 0 (consumed by tr-1)
    __shared__ float xdn[2][6][256];   // each thread's row 5 (consumed by tr+1)

    const int b   = blockIdx.z;
    const int oy  = blockIdx.y * 64;
    const int ox  = blockIdx.x * 64;
    const int tid = threadIdx.x;
    const int tr  = tid >> 4;
    const int tc  = tid & 15;
    const int R0  = tr * 6;
    const int C0  = tc * 6;

    const float* ub = uin + (size_t)b * NN * NN;
    const unsigned char* cb = cmask + (size_t)b * NN * NN;

    float u[6][6];
    float cf[6][6];   // 1.0 = fluid (update), 0.0 = Dirichlet/frozen

    // ---- setup: load 6x6 u + coeffs (clamped; tile ring frozen) ----
#pragma unroll
    for (int r = 0; r < 6; ++r) {
        int ty = R0 + r;
        int gi = oy - HALO + ty;
        gi = min(max(gi, 0), NN - 1);
#pragma unroll
        for (int c = 0; c < 6; ++c) {
            int tx = C0 + c;
            int gj = ox - HALO + tx;
            gj = min(max(gj, 0), NN - 1);
            u[r][c] = ub[gi * NN + gj];
            unsigned m = cb[gi * NN + gj];
            bool ring = (ty == 0) | (ty == LR - 1) | (tx == 0) | (tx == LR - 1);
            cf[r][c] = (ring || m == 0u) ? 0.0f : 1.0f;
        }
    }

    const int tup = (tid >= 16)  ? tid - 16 : tid;   // clamped neighbor indices
    const int tdn = (tid < 240)  ? tid + 16 : tid;

    // ---- TTI fused Jacobi iterations, all in registers ----
#pragma unroll 1
    for (int t = 0; t < TTI; ++t) {
        const int pb = t & 1;
        // publish OLD boundary rows (transposed layout: conflict-free b32)
#pragma unroll
        for (int w = 0; w < 6; ++w) {
            xup[pb][w][tid] = u[0][w];
            xdn[pb][w][tid] = u[5][w];
        }
        // capture OLD horizontal neighbor cols via DPP (pure VALU)
        float lsh[6], rsh[6];
#pragma unroll
        for (int r = 0; r < 6; ++r) {
            lsh[r] = dpp_shr1(u[r][5]);
            rsh[r] = dpp_shl1(u[r][0]);
        }
        __syncthreads();
        float th[6], bh[6];
#pragma unroll
        for (int w = 0; w < 6; ++w) {
            th[w] = xdn[pb][w][tup];   // garbage for tr==0: ring cf=0 kills it
            bh[w] = xup[pb][w][tdn];   // garbage for tr==15: ring cf=0 kills it
        }
        // in-register raster update; orow/prow keep OLD values (pure SSA)
        float prow[6];
#pragma unroll
        for (int c = 0; c < 6; ++c) prow[c] = th[c];
#pragma unroll
        for (int r = 0; r < 6; ++r) {
            float orow[6];
#pragma unroll
            for (int c = 0; c < 6; ++c) orow[c] = u[r][c];
#pragma unroll
            for (int c = 0; c < 6; ++c) {
                float up = prow[c];
                float dn = (r < 5) ? u[r + 1][c] : bh[c];
                float lf = (c > 0) ? orow[c - 1] : lsh[r];
                float rt = (c < 5) ? orow[c + 1] : rsh[r];
                float s  = (up + dn) + (lf + rt);
                float od = orow[c];
                float tq = __builtin_fmaf(0.25f, s, -od);
                u[r][c]  = __builtin_fmaf(cf[r][c], tq, od);
            }
#pragma unroll
            for (int c = 0; c < 6; ++c) prow[c] = orow[c];
        }
    }

    // ---- store center 64x64 (optionally fused epilogue) ----
    float* og = uout + (size_t)b * NN * NN;
    if (!FINAL) {
#pragma unroll
        for (int r = 0; r < 6; ++r) {
            int ty = R0 + r - HALO;
#pragma unroll
            for (int c = 0; c < 6; ++c) {
                int tx = C0 + c - HALO;
                if ((unsigned)ty < 64u && (unsigned)tx < 64u)
                    og[(size_t)(oy + ty) * NN + (ox + tx)] = u[r][c];
            }
        }
    } else {
        float w0  = w_back[0], w1 = w_back[1], bb0 = b_back[0];
        float rs  = 0.25f / (1.0f + expf(-logit[0]));
        float ym  = y_mean[0];
        float ysd = y_std[0] + EPS_F;
        const float4* xm4 = (const float4*)x_mix;
#pragma unroll
        for (int r = 0; r < 6; ++r) {
            int ty = R0 + r - HALO;
#pragma unroll
            for (int c = 0; c < 6; ++c) {
                int tx = C0 + c - HALO;
                if ((unsigned)ty < 64u && (unsigned)tx < 64u) {
                    int gi = oy + ty, gj = ox + tx;
                    size_t gidx = (size_t)b * NN * NN + (size_t)gi * NN + gj;
                    float4 xm = xm4[gidx];
                    float e  = (u[r][c] - ym) / ysd;
                    float rr = xm.x * w0 + xm.y * w1 + bb0;
                    float xs = (float)gi * (1.0f / 511.0f);
                    float ys = (float)gj * (1.0f / 511.0f);
                    float dd = fminf(fminf(xs, 1.0f - xs), fminf(ys, 1.0f - ys));
                    float ww = fminf(fmaxf(dd * (1.0f / DELTA_F), 0.0f), 1.0f);
                    if (xm.z > 0.5f) ww = 0.0f;
                    og[(size_t)gi * NN + gj] = e + ww * rs * rr;
                }
            }
        }
    }
}

// ---------------------------------------------------------------------------
extern "C" void kernel_launch(void* const* d_in, const int* in_sizes, int n_in,
                              void* d_out, int out_size, void* d_ws, size_t ws_size,
                              hipStream_t stream)
{
    const float* x_mix  = (const float*)d_in[0];
    const float* w_back = (const float*)d_in[1];
    const float* b_back = (const float*)d_in[2];
    const float* logit  = (const float*)d_in[3];
    const float* y_mean = (const float*)d_in[4];
    const float* y_std  = (const float*)d_in[5];

    float* out = (float*)d_out;

    // Workspace: u_a (16 MB floats) | cmask (4 MB bytes)
    float* u_a = (float*)d_ws;
    unsigned char* cmask = (unsigned char*)((char*)d_ws + (size_t)TOTAL * sizeof(float));

    const int block = 256;
    const int grid1d = (TOTAL + block - 1) / block;

    init_kernel<<<grid1d, block, 0, stream>>>(x_mix, u_a, cmask);

    // 50 iters = 5 launches x TTI(=10). Chain: a->out->a->out->a->(FINAL)->out
    dim3 sgrid(NN / 64, NN / 64, BB);   // 8 x 8 x 16 = 1024 blocks (4/CU)
    stencil_kernel<false><<<sgrid, block, 0, stream>>>(u_a, out, cmask, x_mix,
        w_back, b_back, logit, y_mean, y_std);
    stencil_kernel<false><<<sgrid, block, 0, stream>>>(out, u_a, cmask, x_mix,
        w_back, b_back, logit, y_mean, y_std);
    stencil_kernel<false><<<sgrid, block, 0, stream>>>(u_a, out, cmask, x_mix,
        w_back, b_back, logit, y_mean, y_std);
    stencil_kernel<false><<<sgrid, block, 0, stream>>>(out, u_a, cmask, x_mix,
        w_back, b_back, logit, y_mean, y_std);
    stencil_kernel<true><<<sgrid, block, 0, stream>>>(u_a, out, cmask, x_mix,
        w_back, b_back, logit, y_mean, y_std);
}